// Round 8
// baseline (4026.332 us; speedup 1.0000x reference)
//
#include <hip/hip_runtime.h>
#include <stdint.h>

#define TN_D 1024
#define TN_F 1024
#define SENT32 0xAAAAAAAAu
#define NBLK 128
#define CPB 8  // columns per block (1 per compute wave; waves 8-9 poll)

typedef _Float16 half4_t __attribute__((ext_vector_type(4)));

// Raw workgroup barrier WITHOUT the vmcnt(0) drain __syncthreads carries.
// LDS writes are flushed (lgkmcnt(0)); vmem loads/stores stay in flight, so
// multi-step register prefetch survives the barrier (m139 technique).
#define ASMBAR() __asm__ volatile("s_waitcnt lgkmcnt(0)\n\ts_barrier" ::: "memory")

__device__ __forceinline__ float dot4h(float4 v, half4_t m) {
    return v.x * (float)m[0] + v.y * (float)m[1] + v.z * (float)m[2] + v.w * (float)m[3];
}

// ---------------------------------------------------------------------------
// Transpose + convert: core[s][i][j] f32 -> coreT[s][j][i] f16.
// ---------------------------------------------------------------------------
__global__ __launch_bounds__(256) void tn_transpose(const float* __restrict__ core,
                                                    _Float16* __restrict__ coreT) {
    __shared__ float tile[64][65];
    const int s = blockIdx.z;
    const size_t base = (size_t)s * TN_D * TN_D;
    const int j0 = blockIdx.x * 64;
    const int i0 = blockIdx.y * 64;
    const int tx = threadIdx.x;
    const int ty = threadIdx.y;
#pragma unroll
    for (int r = 0; r < 4; ++r) {
        const int ii = ty + 16 * r;
        const float4 v = *(const float4*)&core[base + (size_t)(i0 + ii) * TN_D + j0 + 4 * tx];
        tile[ii][4 * tx + 0] = v.x; tile[ii][4 * tx + 1] = v.y;
        tile[ii][4 * tx + 2] = v.z; tile[ii][4 * tx + 3] = v.w;
    }
    __syncthreads();
#pragma unroll
    for (int r = 0; r < 4; ++r) {
        const int jj = ty + 16 * r;
        _Float16 h4[4];
        h4[0] = (_Float16)tile[4 * tx + 0][jj];
        h4[1] = (_Float16)tile[4 * tx + 1][jj];
        h4[2] = (_Float16)tile[4 * tx + 2][jj];
        h4[3] = (_Float16)tile[4 * tx + 3][jj];
        *(uint64_t*)&coreT[base + (size_t)(j0 + jj) * TN_D + i0 + 4 * tx] = *(uint64_t*)h4;
    }
}

__device__ __forceinline__ float poll1(const uint32_t* p) {
    uint32_t u = __hip_atomic_load(p, __ATOMIC_RELAXED, __HIP_MEMORY_SCOPE_AGENT);
    while (u == SENT32)
        u = __hip_atomic_load(p, __ATOMIC_RELAXED, __HIP_MEMORY_SCOPE_AGENT);
    return __uint_as_float(u);
}

// ---------------------------------------------------------------------------
// Persistent chain, f16 matrix. 128 blocks x 640 threads (10 waves).
// Waves 0..7 = compute: wave w owns column j = 8*blk + w. Their vmem queue
// holds ONLY matrix loads (2-step register lookahead, counted vmcnt waits)
// + 4B publish stores — never inspected early.
// Waves 8..9 = pollers: 128 threads; thread p handles 8B chunks 4p..4p+3 of
// the v-row (skipping p == blockIdx.x, whose 8 floats arrive via compute
// lane0 LDS deposits). Their vmem queue holds ONLY poll loads.
// Raw lgkm-only barriers: no vmcnt drain anywhere in the loop.
// Interval (B^t, B^{t+1}): compute(t) reads lv[t&1], deposits lv[(t+1)&1][j],
// publishes row t; pollers poll row t (remote chunks) -> lv[(t+1)&1].
// lv[t&1] is next overwritten after B^{t+1} (staging row t+1's successor),
// by which time its readers have passed B^{t+1}.  No races.
// ---------------------------------------------------------------------------
__global__ __launch_bounds__(640, 1) void tn_chain_f16(const int* __restrict__ x,
                                                       const _Float16* __restrict__ mat,
                                                       const float* __restrict__ left,
                                                       const float* __restrict__ right,
                                                       float* __restrict__ vg,
                                                       float* __restrict__ out) {
    __shared__ float lv[2][TN_D];  // 8 KB double-buffered v
    __shared__ int xs[TN_F];       // 4 KB symbol stream
    __shared__ float red[CPB];

    const int tid = threadIdx.x;
    const int w = tid >> 6;
    const int l = tid & 63;

    if (tid < 256) ((int4*)xs)[tid] = ((const int4*)x)[tid];
    __syncthreads();

    if (w < CPB) {
        // ======================= compute waves =======================
        const int j = blockIdx.x * CPB + w;
        half4_t A0, A1, A2, A3, B0, B1, B2, B3;
        {
            const _Float16* cp = mat + ((size_t)xs[0] * TN_D + j) * TN_D;
            A0 = *(const half4_t*)(cp + 4 * l);
            A1 = *(const half4_t*)(cp + 4 * l + 256);
            A2 = *(const half4_t*)(cp + 4 * l + 512);
            A3 = *(const half4_t*)(cp + 4 * l + 768);
        }
        {
            const _Float16* cp = mat + ((size_t)xs[1] * TN_D + j) * TN_D;
            B0 = *(const half4_t*)(cp + 4 * l);
            B1 = *(const half4_t*)(cp + 4 * l + 256);
            B2 = *(const half4_t*)(cp + 4 * l + 512);
            B3 = *(const half4_t*)(cp + 4 * l + 768);
        }
        for (int t = 0; t < TN_F; t += 2) {
            const int s2 = xs[(t + 2 < TN_F) ? t + 2 : TN_F - 1];
            const int s3 = xs[(t + 3 < TN_F) ? t + 3 : TN_F - 1];

            // ---------- even step t (registers A, v in lv[0]) ----------
            ASMBAR();  // B^t : lv[0] staged
            {
                const float4* vv = (const float4*)lv[0];
                float acc = dot4h(vv[l], A0) + dot4h(vv[l + 64], A1) +
                            dot4h(vv[l + 128], A2) + dot4h(vv[l + 192], A3);
#pragma unroll
                for (int off = 32; off; off >>= 1) acc += __shfl_down(acc, off, 64);
                if (l == 0) {
                    lv[1][j] = acc;  // local deposit (pollers skip own chunks)
                    __hip_atomic_store((uint32_t*)vg + (size_t)t * TN_D + j,
                                       __float_as_uint(acc), __ATOMIC_RELAXED,
                                       __HIP_MEMORY_SCOPE_AGENT);
                }
                // reload A for step t+2 (issue AFTER last use; 2-interval slack)
                const _Float16* cp = mat + ((size_t)s2 * TN_D + j) * TN_D;
                A0 = *(const half4_t*)(cp + 4 * l);
                A1 = *(const half4_t*)(cp + 4 * l + 256);
                A2 = *(const half4_t*)(cp + 4 * l + 512);
                A3 = *(const half4_t*)(cp + 4 * l + 768);
            }

            // ---------- odd step t+1 (registers B, v in lv[1]) ----------
            ASMBAR();  // B^{t+1} : lv[1] staged
            {
                const float4* vv = (const float4*)lv[1];
                float acc = dot4h(vv[l], B0) + dot4h(vv[l + 64], B1) +
                            dot4h(vv[l + 128], B2) + dot4h(vv[l + 192], B3);
#pragma unroll
                for (int off = 32; off; off >>= 1) acc += __shfl_down(acc, off, 64);
                if (l == 0) {
                    lv[0][j] = acc;
                    __hip_atomic_store((uint32_t*)vg + (size_t)(t + 1) * TN_D + j,
                                       __float_as_uint(acc), __ATOMIC_RELAXED,
                                       __HIP_MEMORY_SCOPE_AGENT);
                }
                const _Float16* cp = mat + ((size_t)s3 * TN_D + j) * TN_D;
                B0 = *(const half4_t*)(cp + 4 * l);
                B1 = *(const half4_t*)(cp + 4 * l + 256);
                B2 = *(const half4_t*)(cp + 4 * l + 512);
                B3 = *(const half4_t*)(cp + 4 * l + 768);
            }
        }
    } else {
        // ======================= poller waves =======================
        const int p = tid - 512;  // 0..127 ; handles 8B chunks 4p..4p+3
        const bool own = (p == blockIdx.x);
        {   // stage left -> lv[0] (pristine input, plain loads fine)
            const float4* lp = (const float4*)left;
            float4 a = lp[2 * p], b = lp[2 * p + 1];
            ((float4*)lv[0])[2 * p] = a;
            ((float4*)lv[0])[2 * p + 1] = b;
        }
        for (int t = 0; t < TN_F; t += 2) {
            ASMBAR();  // B^t
            if (!own) {  // poll row t -> lv[1]
                const unsigned long long* bp =
                    (const unsigned long long*)(vg + (size_t)t * TN_D) + 4 * p;
                unsigned long long u[4];
#pragma unroll
                for (int k = 0; k < 4; ++k)
                    u[k] = __hip_atomic_load(bp + k, __ATOMIC_RELAXED,
                                             __HIP_MEMORY_SCOPE_AGENT);
#pragma unroll
                for (int k = 0; k < 4; ++k)
                    while ((uint32_t)u[k] == SENT32 || (uint32_t)(u[k] >> 32) == SENT32)
                        u[k] = __hip_atomic_load(bp + k, __ATOMIC_RELAXED,
                                                 __HIP_MEMORY_SCOPE_AGENT);
                unsigned long long* d = (unsigned long long*)lv[1] + 4 * p;
#pragma unroll
                for (int k = 0; k < 4; ++k) d[k] = u[k];
            }
            ASMBAR();  // B^{t+1}
            if (!own && t + 2 < TN_F) {  // poll row t+1 -> lv[0]
                const unsigned long long* bp =
                    (const unsigned long long*)(vg + (size_t)(t + 1) * TN_D) + 4 * p;
                unsigned long long u[4];
#pragma unroll
                for (int k = 0; k < 4; ++k)
                    u[k] = __hip_atomic_load(bp + k, __ATOMIC_RELAXED,
                                             __HIP_MEMORY_SCOPE_AGENT);
#pragma unroll
                for (int k = 0; k < 4; ++k)
                    while ((uint32_t)u[k] == SENT32 || (uint32_t)(u[k] >> 32) == SENT32)
                        u[k] = __hip_atomic_load(bp + k, __ATOMIC_RELAXED,
                                                 __HIP_MEMORY_SCOPE_AGENT);
                unsigned long long* d = (unsigned long long*)lv[0] + 4 * p;
#pragma unroll
                for (int k = 0; k < 4; ++k) d[k] = u[k];
            }
        }
    }

    // ---- final dot with right boundary: block 0 ----
    if (blockIdx.x == 0) {
        if (tid < 512) {
            float v0 = poll1((const uint32_t*)vg + (size_t)(TN_F - 1) * TN_D + tid);
            float v1 = poll1((const uint32_t*)vg + (size_t)(TN_F - 1) * TN_D + tid + 512);
            float pr = v0 * right[tid] + v1 * right[tid + 512];
#pragma unroll
            for (int off = 32; off; off >>= 1) pr += __shfl_down(pr, off, 64);
            if (l == 0) red[w] = pr;
        }
        ASMBAR();
        if (tid == 0) {
            float s = 0.f;
#pragma unroll
            for (int k = 0; k < CPB; ++k) s += red[k];
            out[0] = s;
        }
    }
}

// ---------------------------------------------------------------------------
// Fallback (tiny workspace): R2-structure fp32, no transpose.
// ---------------------------------------------------------------------------
__device__ __forceinline__ float4 poll4(const uint32_t* vp) {
    const unsigned long long* p = (const unsigned long long*)vp;
    unsigned long long a = __hip_atomic_load(p, __ATOMIC_RELAXED, __HIP_MEMORY_SCOPE_AGENT);
    unsigned long long b = __hip_atomic_load(p + 1, __ATOMIC_RELAXED, __HIP_MEMORY_SCOPE_AGENT);
    while ((uint32_t)a == SENT32 || (uint32_t)(a >> 32) == SENT32)
        a = __hip_atomic_load(p, __ATOMIC_RELAXED, __HIP_MEMORY_SCOPE_AGENT);
    while ((uint32_t)b == SENT32 || (uint32_t)(b >> 32) == SENT32)
        b = __hip_atomic_load(p + 1, __ATOMIC_RELAXED, __HIP_MEMORY_SCOPE_AGENT);
    return make_float4(__uint_as_float((uint32_t)a), __uint_as_float((uint32_t)(a >> 32)),
                       __uint_as_float((uint32_t)b), __uint_as_float((uint32_t)(b >> 32)));
}

__global__ __launch_bounds__(256, 1) void tn_chain_f32(const int* __restrict__ x,
                                                       const float* __restrict__ mat,
                                                       const float* __restrict__ left,
                                                       const float* __restrict__ right,
                                                       float* __restrict__ vg,
                                                       float* __restrict__ out) {
    __shared__ float4 lv[2][TN_D / 4];
    __shared__ float red[4];
    const int tid = threadIdx.x;
    const int w = tid >> 6;
    const int l = tid & 63;
    const int j = blockIdx.x * 4 + w;

    for (int t = 0; t < TN_F; ++t) {
        if (t == 0) lv[0][tid] = ((const float4*)left)[tid];
        else lv[t & 1][tid] = poll4((const uint32_t*)vg + (size_t)(t - 1) * TN_D + 4 * tid);
        __syncthreads();
        const float* mp = mat + (size_t)x[t] * TN_D * TN_D + j;
        const float4* vv = lv[t & 1];
        float acc = 0.f;
#pragma unroll
        for (int k = 0; k < 4; ++k) {
            const int i = 4 * l + 256 * k;
            const float4 v = vv[l + 64 * k];
            acc += v.x * mp[(size_t)i * TN_D] + v.y * mp[(size_t)(i + 1) * TN_D] +
                   v.z * mp[(size_t)(i + 2) * TN_D] + v.w * mp[(size_t)(i + 3) * TN_D];
        }
#pragma unroll
        for (int off = 32; off; off >>= 1) acc += __shfl_down(acc, off, 64);
        if (l == 0)
            __hip_atomic_store((uint32_t*)vg + (size_t)t * TN_D + j, __float_as_uint(acc),
                               __ATOMIC_RELAXED, __HIP_MEMORY_SCOPE_AGENT);
    }
    if (blockIdx.x == 0) {
        float4 v = poll4((const uint32_t*)vg + (size_t)(TN_F - 1) * TN_D + 4 * tid);
        const float4 r4 = ((const float4*)right)[tid];
        float p = v.x * r4.x + v.y * r4.y + v.z * r4.z + v.w * r4.w;
#pragma unroll
        for (int off = 32; off; off >>= 1) p += __shfl_down(p, off, 64);
        if (l == 0) red[w] = p;
        __syncthreads();
        if (tid == 0) out[0] = red[0] + red[1] + red[2] + red[3];
    }
}

extern "C" void kernel_launch(void* const* d_in, const int* in_sizes, int n_in,
                              void* d_out, int out_size, void* d_ws, size_t ws_size,
                              hipStream_t stream) {
    const int* x = (const int*)d_in[0];
    const float* core = (const float*)d_in[1];
    const float* left = (const float*)d_in[2];
    const float* right = (const float*)d_in[3];
    float* out = (float*)d_out;

    const int nsym = in_sizes[1] / (TN_D * TN_D);
    const size_t coreTBytes = (size_t)in_sizes[1] * sizeof(_Float16);  // 64 MB
    const size_t vbufBytes = (size_t)TN_F * TN_D * sizeof(float);      // 4 MB

    if (ws_size >= coreTBytes + vbufBytes) {
        _Float16* coreT = (_Float16*)d_ws;
        float* vg = (float*)((char*)d_ws + coreTBytes);
        hipMemsetAsync(vg, 0xAA, vbufBytes, stream);
        tn_transpose<<<dim3(16, 16, nsym), dim3(16, 16), 0, stream>>>(core, coreT);
        tn_chain_f16<<<NBLK, 640, 0, stream>>>(x, coreT, left, right, vg, out);
    } else {
        float* vg = (float*)d_ws;
        hipMemsetAsync(vg, 0xAA, vbufBytes, stream);
        tn_chain_f32<<<256, 256, 0, stream>>>(x, core, left, right, vg, out);
    }
}